// Round 8
// baseline (85.029 us; speedup 1.0000x reference)
//
#include <hip/hip_runtime.h>

// ---------------------------------------------------------------------------
// MixModel, 3 threads/row-segment, 2 rows per thread (rows p and p+nh).
// Ladder: R1 136VGPR 127us | R2-R4 spill 155-159 | R6 scalar 60VGPR 76us
//         R7 pk-f32 36VGPR 74.8us (VALUBusy 46%, HBM 30% -> latency-bound)
// R8: two independent row-chains per thread for ILP. Windows for both rows
//     loaded up-front (10 float4 in flight), then compute/store each.
//     pk math kept (fewer issue slots); VGPR est ~80. Spill signature:
//     WRITE_SIZE >> 140,625 KB -> revert.
// ---------------------------------------------------------------------------

typedef float f2 __attribute__((ext_vector_type(2)));

__device__ __forceinline__ f2 splat2(float x) { f2 v; v.x = x; v.y = x; return v; }
__device__ __forceinline__ f2 mk2(float a, float b) { f2 v; v.x = a; v.y = b; return v; }
__device__ __forceinline__ f2 fma2(f2 a, f2 b, f2 c) { return __builtin_elementwise_fma(a, b, c); }
__device__ __forceinline__ f2 relu2(f2 a) { return __builtin_elementwise_max(a, splat2(0.0f)); }

// Packed MLP 3->3->6->3 for a pair of positions.
__device__ __forceinline__ void mlp_a2(f2 x0, f2 x1, f2 x2,
                                       const float* __restrict__ w0, const float* __restrict__ b0,
                                       const float* __restrict__ w1, const float* __restrict__ b1,
                                       const float* __restrict__ w2, const float* __restrict__ b2,
                                       f2& o0, f2& o1, f2& o2)
{
    f2 h0[3];
#pragma unroll
    for (int q = 0; q < 3; ++q) {
        f2 a = fma2(x0, splat2(w0[q*3+0]), splat2(b0[q]));
        a = fma2(x1, splat2(w0[q*3+1]), a);
        a = fma2(x2, splat2(w0[q*3+2]), a);
        h0[q] = relu2(a);
    }
    f2 h1[6];
#pragma unroll
    for (int q = 0; q < 6; ++q) {
        f2 a = fma2(h0[0], splat2(w1[q*3+0]), splat2(b1[q]));
        a = fma2(h0[1], splat2(w1[q*3+1]), a);
        a = fma2(h0[2], splat2(w1[q*3+2]), a);
        h1[q] = relu2(a);
    }
    f2 t[3];
#pragma unroll
    for (int q = 0; q < 3; ++q) {
        f2 a = fma2(h1[0], splat2(w2[q*6+0]), splat2(b2[q]));
#pragma unroll
        for (int i = 1; i < 6; ++i) a = fma2(h1[i], splat2(w2[q*6+i]), a);
        t[q] = a;
    }
    o0 = t[0]; o1 = t[1]; o2 = t[2];
}

// Packed MLP 4->4->6->2 for a pair of positions.
__device__ __forceinline__ void mlp_b2(f2 x0, f2 x1, f2 x2, f2 x3,
                                       const float* __restrict__ w0, const float* __restrict__ b0,
                                       const float* __restrict__ w1, const float* __restrict__ b1,
                                       const float* __restrict__ w2, const float* __restrict__ b2,
                                       f2& o0, f2& o1)
{
    f2 h0[4];
#pragma unroll
    for (int q = 0; q < 4; ++q) {
        f2 a = fma2(x0, splat2(w0[q*4+0]), splat2(b0[q]));
        a = fma2(x1, splat2(w0[q*4+1]), a);
        a = fma2(x2, splat2(w0[q*4+2]), a);
        a = fma2(x3, splat2(w0[q*4+3]), a);
        h0[q] = relu2(a);
    }
    f2 h1[6];
#pragma unroll
    for (int q = 0; q < 6; ++q) {
        f2 a = fma2(h0[0], splat2(w1[q*4+0]), splat2(b1[q]));
        a = fma2(h0[1], splat2(w1[q*4+1]), a);
        a = fma2(h0[2], splat2(w1[q*4+2]), a);
        a = fma2(h0[3], splat2(w1[q*4+3]), a);
        h1[q] = relu2(a);
    }
    f2 t[2];
#pragma unroll
    for (int q = 0; q < 2; ++q) {
        f2 a = fma2(h1[0], splat2(w2[q*6+0]), splat2(b2[q]));
#pragma unroll
        for (int i = 1; i < 6; ++i) a = fma2(h1[i], splat2(w2[q*6+i]), a);
        t[q] = a;
    }
    o0 = t[0]; o1 = t[1];
}

// Compute one (row, r) segment from its 20-col window; store 12 cols.
__device__ __forceinline__ void compute_seg(
    const float* __restrict__ w_, const float* __restrict__ rb, f2 r02,
    const float* __restrict__ w10, const float* __restrict__ b10,
    const float* __restrict__ w11, const float* __restrict__ b11,
    const float* __restrict__ w12, const float* __restrict__ b12,
    const float* __restrict__ w20, const float* __restrict__ b20,
    const float* __restrict__ w21, const float* __restrict__ b21,
    const float* __restrict__ w22, const float* __restrict__ b22,
    const float* __restrict__ w30, const float* __restrict__ b30,
    const float* __restrict__ w31, const float* __restrict__ b31,
    const float* __restrict__ w32, const float* __restrict__ b32,
    float4* __restrict__ o4)
{
#define W(k) w_[(k) + 4]
    f2 c0[2], c1[2], c2[2];   // pair P covers jj = 2P, 2P+1

#pragma unroll
    for (int P = 0; P < 2; ++P) {
        const int q = 6 * P;
        f2 a0, a1, a2;
        mlp_a2(mk2(W(q - 2), W(q + 1)), mk2(W(q), W(q + 3)), mk2(W(q + 1), W(q + 4)),
               w10, b10, w11, b11, w12, b12, a0, a1, a2);
        const f2 ua = mk2(W(q - 1), W(q + 2));
        const f2 ub = mk2(W(q + 2), W(q + 5));
        const f2 rv = mk2(rb[q + 1], rb[q + 4]);
        const f2 uv = mk2(W(q), W(q + 3));
        c0[P] = fma2(uv, rv, r02) + fma2(a2, ub, fma2(a1, ua, a0));
    }
#pragma unroll
    for (int P = 0; P < 2; ++P) {
        const int q = 6 * P;
        f2 a0, a1, a2;
        mlp_a2(mk2(W(q), W(q + 3)), mk2(W(q + 1), W(q + 4)), mk2(W(q + 3), W(q + 6)),
               w20, b20, w21, b21, w22, b22, a0, a1, a2);
        const f2 ua = mk2(W(q - 1), W(q + 2));
        const f2 ub = mk2(W(q + 2), W(q + 5));
        const f2 rv = mk2(rb[q + 2], rb[q + 5]);
        const f2 uv = mk2(W(q + 1), W(q + 4));
        c1[P] = fma2(uv, rv, r02) + fma2(a2, ub, fma2(a1, ua, a0));
    }
#pragma unroll
    for (int P = 0; P < 2; ++P) {
        const int q = 6 * P;
        f2 d0, d1;
        mlp_b2(mk2(W(q), W(q + 3)), mk2(W(q + 1), W(q + 4)),
               mk2(W(q + 3), W(q + 6)), mk2(W(q + 4), W(q + 7)),
               w30, b30, w31, b31, w32, b32, d0, d1);
        const f2 ub = mk2(W(q + 2), W(q + 5));
        const f2 rv = mk2(rb[q + 3], rb[q + 6]);
        c2[P] = fma2(ub, rv, r02) + fma2(d1, ub, d0);
    }
#undef W

    o4[0] = make_float4(c0[0].x, c1[0].x, c2[0].x, c0[0].y);
    o4[1] = make_float4(c1[0].y, c2[0].y, c0[1].x, c1[1].x);
    o4[2] = make_float4(c2[1].x, c0[1].y, c1[1].y, c2[1].y);
}

__global__ __launch_bounds__(256) void mixmodel_kernel(
    const float* __restrict__ u, const float* __restrict__ reg,
    const float* __restrict__ w10, const float* __restrict__ b10,
    const float* __restrict__ w11, const float* __restrict__ b11,
    const float* __restrict__ w12, const float* __restrict__ b12,
    const float* __restrict__ w20, const float* __restrict__ b20,
    const float* __restrict__ w21, const float* __restrict__ b21,
    const float* __restrict__ w22, const float* __restrict__ b22,
    const float* __restrict__ w30, const float* __restrict__ b30,
    const float* __restrict__ w31, const float* __restrict__ b31,
    const float* __restrict__ w32, const float* __restrict__ b32,
    float* __restrict__ out, int nh, int n)
{
    const int tid = blockIdx.x * blockDim.x + threadIdx.x;
    if (tid >= 3 * nh) return;
    const int p = tid / 3;             // pair index
    const int r = tid - 3 * p;         // 0..2 -> output cols 12r..12r+11
    const int rowA = p;
    const int rowB = p + nh;           // may be >= n only if n odd
    const bool hasB = (rowB < n);

    // ---- load both 20-col windows up-front (10 loads in flight) ----
    float wA[20], wB[20];
    {
        const float4* __restrict__ uA = reinterpret_cast<const float4*>(u + (size_t)rowA * 36);
        const float4* __restrict__ uB = reinterpret_cast<const float4*>(u + (size_t)rowB * 36);
#pragma unroll
        for (int t = 0; t < 5; ++t) {
            int idx = 3 * r + 8 + t;           // 8..18
            if (idx >= 9) idx -= 9;            // 0..9
            if (idx >= 9) idx -= 9;            // 0..8 (double wrap)
            const float4 va = uA[idx];
            wA[4*t+0] = va.x; wA[4*t+1] = va.y; wA[4*t+2] = va.z; wA[4*t+3] = va.w;
            if (hasB) {
                const float4 vb = uB[idx];
                wB[4*t+0] = vb.x; wB[4*t+1] = vb.y; wB[4*t+2] = vb.z; wB[4*t+3] = vb.w;
            }
        }
    }

    const float r0 = reg[0];
    const f2 r02 = splat2(r0);
    const float* __restrict__ rb = reg + 12 * r;

    compute_seg(wA, rb, r02,
                w10, b10, w11, b11, w12, b12,
                w20, b20, w21, b21, w22, b22,
                w30, b30, w31, b31, w32, b32,
                reinterpret_cast<float4*>(out + (size_t)rowA * 36 + 12 * r));
    if (hasB)
        compute_seg(wB, rb, r02,
                    w10, b10, w11, b11, w12, b12,
                    w20, b20, w21, b21, w22, b22,
                    w30, b30, w31, b31, w32, b32,
                    reinterpret_cast<float4*>(out + (size_t)rowB * 36 + 12 * r));
}

extern "C" void kernel_launch(void* const* d_in, const int* in_sizes, int n_in,
                              void* d_out, int out_size, void* d_ws, size_t ws_size,
                              hipStream_t stream)
{
    const float* u   = (const float*)d_in[1];
    const float* reg = (const float*)d_in[2];
    const float* w10 = (const float*)d_in[3];
    const float* b10 = (const float*)d_in[4];
    const float* w11 = (const float*)d_in[5];
    const float* b11 = (const float*)d_in[6];
    const float* w12 = (const float*)d_in[7];
    const float* b12 = (const float*)d_in[8];
    const float* w20 = (const float*)d_in[9];
    const float* b20 = (const float*)d_in[10];
    const float* w21 = (const float*)d_in[11];
    const float* b21 = (const float*)d_in[12];
    const float* w22 = (const float*)d_in[13];
    const float* b22 = (const float*)d_in[14];
    const float* w30 = (const float*)d_in[15];
    const float* b30 = (const float*)d_in[16];
    const float* w31 = (const float*)d_in[17];
    const float* b31 = (const float*)d_in[18];
    const float* w32 = (const float*)d_in[19];
    const float* b32 = (const float*)d_in[20];
    float* out = (float*)d_out;

    const int n  = in_sizes[1] / 36;   // 1,000,000 rows
    const int nh = (n + 1) / 2;        // rows per half
    const int nt = 3 * nh;             // threads
    const int block = 256;
    const int grid = (nt + block - 1) / block;

    hipLaunchKernelGGL(mixmodel_kernel, dim3(grid), dim3(block), 0, stream,
                       u, reg, w10, b10, w11, b11, w12, b12,
                       w20, b20, w21, b21, w22, b22,
                       w30, b30, w31, b31, w32, b32, out, nh, n);
}